// Round 3
// baseline (322.146 us; speedup 1.0000x reference)
//
#include <hip/hip_runtime.h>
#include <hip/hip_cooperative_groups.h>

namespace cg = cooperative_groups;

// Problem constants (match reference)
#define BATCH 4
#define QLEN 2048
#define CLEN 2048
#define DIM 512
#define NBLK 1024
#define CHPB 256            // chunks per batch in phase 1 (NBLK / BATCH)
#define ROWS_PC 8           // rows per chunk (CLEN / CHPB)

// The reference collapses: einsum 'bqkh,bvha->bqha' has independent k and v,
// and softmax over k sums to exactly 1, so
//   out[b,q,:] = ((sum_cl context[b,cl,:]) @ Wkv[:,D:2D]) @ Wout   for every q.
// query, Wq, mask are dead inputs.
// Single cooperative launch, 4 phases over 3 grid syncs.

__global__ __launch_bounds__(256, 4) void fused_all(
    const float* __restrict__ ctx,
    const float* __restrict__ Wkv,
    const float* __restrict__ Wout,
    float* __restrict__ partial,    // NBLK*DIM floats
    float* __restrict__ vpart,      // 4*BATCH*DIM floats
    float* __restrict__ orow,       // BATCH*DIM floats
    float4* __restrict__ out)
{
    __shared__ float smem[1024];    // 4 KB, re-used per phase
    const int blk = blockIdx.x;
    const int t   = threadIdx.x;
    cg::grid_group grid = cg::this_grid();

    // ---- Phase 1: per-block partial column sums (8 context rows each) ----
    {
        const int b  = blk >> 8;        // /CHPB
        const int ch = blk & 255;
        const int rg = t >> 7;          // 0..1
        const int f4 = t & 127;
        const float4* p = reinterpret_cast<const float4*>(
            ctx + ((size_t)(b * CLEN + ch * ROWS_PC + rg * 4)) * DIM) + f4;
        float4 s = make_float4(0.f, 0.f, 0.f, 0.f);
#pragma unroll
        for (int r = 0; r < 4; ++r) {
            float4 x = p[(size_t)r * (DIM / 4)];
            s.x += x.x; s.y += x.y; s.z += x.z; s.w += x.w;
        }
        float4* red4 = reinterpret_cast<float4*>(smem);
        red4[t] = s;
        __syncthreads();
        if (t < 128) {
            float4 a = red4[t], c = red4[t + 128];
            reinterpret_cast<float4*>(partial)[(size_t)blk * (DIM / 4) + t] =
                make_float4(a.x + c.x, a.y + c.y, a.z + c.z, a.w + c.w);
        }
    }
    grid.sync();

    // ---- Phase 2 (blocks 0..31): reduce partial -> csum slice; V matvec ----
    // vpart[ks][b][e] = sum_{d in slice ks} csum[b][d] * Wkv[d][512+e]
    if (blk < 32) {
        const int ks = blk >> 3;
        const int ec = blk & 7;
        if (t < 128) {
            const int bb = t >> 5, f4l = t & 31;
            const float4* p4 = reinterpret_cast<const float4*>(partial)
                             + (size_t)(bb * CHPB) * (DIM / 4) + ks * 32 + f4l;
            float4 s = make_float4(0.f, 0.f, 0.f, 0.f);
#pragma unroll 8
            for (int ch = 0; ch < CHPB; ++ch) {
                float4 x = p4[(size_t)ch * (DIM / 4)];
                s.x += x.x; s.y += x.y; s.z += x.z; s.w += x.w;
            }
            reinterpret_cast<float4*>(smem)[bb * 32 + f4l] = s;  // cs[bb][128]
        }
        __syncthreads();
        const int b = t >> 6, el = t & 63;      // wave-uniform b -> LDS broadcast
        const int e = ec * 64 + el;
        const float* w  = Wkv + (size_t)(ks * 128) * (2 * DIM) + DIM + e;
        const float* cs = smem + b * 128;
        float s = 0.f;
#pragma unroll 8
        for (int d0 = 0; d0 < 128; ++d0) s += cs[d0] * w[(size_t)d0 * (2 * DIM)];
        vpart[(ks * BATCH + b) * DIM + e] = s;
    }
    grid.sync();

    // ---- Phase 3 (blocks 0..31): vsum combine + orow matvec ----
    if (blk < 32) {
        const int b  = blk >> 3;
        const int fc = blk & 7;
        float* vs = smem;               // [512]
        for (int j = t; j < DIM; j += 256) {
            const int idx = b * DIM + j;
            vs[j] = vpart[idx] + vpart[BATCH * DIM + idx]
                  + vpart[2 * BATCH * DIM + idx] + vpart[3 * BATCH * DIM + idx];
        }
        __syncthreads();
        const int fl = t & 63, eq = t >> 6;
        const float* w = Wout + (size_t)(eq * 128) * DIM + fc * 64 + fl;
        float s = 0.f;
#pragma unroll 8
        for (int e0 = 0; e0 < 128; ++e0) s += vs[eq * 128 + e0] * w[(size_t)e0 * DIM];
        float* redf = smem + 512;
        redf[t] = s;
        __syncthreads();
        if (t < 64)
            orow[b * DIM + fc * 64 + t] =
                redf[t] + redf[64 + t] + redf[128 + t] + redf[192 + t];
    }
    grid.sync();

    // ---- Phase 4: broadcast orow over all q ----
    {
        const int b  = blk >> 8;
        const int qg = blk & 255;
        const int rg = t >> 7, f4 = t & 127;
        const float4 val = reinterpret_cast<const float4*>(orow)[b * (DIM / 4) + f4];
        float4* dst = out + ((size_t)(b * QLEN + qg * ROWS_PC + rg * 4)) * (DIM / 4) + f4;
#pragma unroll
        for (int r = 0; r < 4; ++r) dst[(size_t)r * (DIM / 4)] = val;
    }
}

extern "C" void kernel_launch(void* const* d_in, const int* in_sizes, int n_in,
                              void* d_out, int out_size, void* d_ws, size_t ws_size,
                              hipStream_t stream) {
    // inputs: 0=query (unused), 1=context, 2=mask (unused), 3=Wq (unused), 4=Wkv, 5=Wout
    const float* ctx  = (const float*)d_in[1];
    const float* Wkv  = (const float*)d_in[4];
    const float* Wout = (const float*)d_in[5];
    float* ws = (float*)d_ws;
    float* partial = ws;                                  // NBLK*DIM      = 524288 f
    float* vpart   = partial + NBLK * DIM;                // 4*BATCH*DIM   = 8192 f
    float* orow    = vpart + 4 * BATCH * DIM;             // BATCH*DIM     = 2048 f
    float4* out    = (float4*)d_out;

    void* args[] = {(void*)&ctx, (void*)&Wkv, (void*)&Wout,
                    (void*)&partial, (void*)&vpart, (void*)&orow, (void*)&out};
    hipLaunchCooperativeKernel((const void*)fused_all, dim3(NBLK), dim3(256),
                               args, 0, stream);
}

// Round 4
// 259.614 us; speedup vs baseline: 1.2409x; 1.2409x over previous
//
#include <hip/hip_runtime.h>

// Problem constants (match reference)
#define BATCH 4
#define QLEN 2048
#define CLEN 2048
#define DIM 512
#define NBLK 1024
#define CPB 256            // chunks per batch (NBLK / BATCH)
#define RPC 8              // context/out rows per chunk (CLEN / CPB)

// The reference collapses: einsum 'bqkh,bvha->bqha' has independent k and v,
// and softmax over k sums to exactly 1, so
//   out[b,q,:] = ((sum_cl context[b,cl,:]) @ Wkv[:,D:2D]) @ Wout   for every q.
// query, Wq, mask are dead inputs.
//
// Single REGULAR launch; phases linked by hand-rolled device-scope sync
// (threadfence + integer counters + relaxed-poll), NOT cg::grid.sync
// (measured ~100us/sync in round 3). 1024 blocks @ 4/CU => all co-resident.

__device__ __forceinline__ unsigned poll_ld(const unsigned* p) {
    return __hip_atomic_load(p, __ATOMIC_RELAXED, __HIP_MEMORY_SCOPE_AGENT);
}

__global__ __launch_bounds__(256, 4) void fused_sync(
    const float* __restrict__ ctx, const float* __restrict__ Wkv,
    const float* __restrict__ Wout, float* __restrict__ partial,
    float* __restrict__ vpart, float* __restrict__ orow,
    unsigned* __restrict__ ctr, float4* __restrict__ out)
{
    __shared__ float4 smem4[256];              // 4 KB, reused per phase
    float* smem = reinterpret_cast<float*>(smem4);
    const int blk = blockIdx.x, t = threadIdx.x;
    const int b_hi = blk >> 8;                 // batch
    const int sub  = blk & 255;                // chunk within batch

    // ---- Phase A: partial column sums of context (16.8 MB read) ----
    {
        const int rg = t >> 7, f4 = t & 127;   // row-group 0..1, float4 col
        const float4* src = reinterpret_cast<const float4*>(ctx)
                          + (size_t)(b_hi * CLEN + sub * RPC) * (DIM / 4);
        float4 s = make_float4(0.f, 0.f, 0.f, 0.f);
#pragma unroll
        for (int i = 0; i < 4; ++i) {
            float4 x = src[(size_t)(rg + 2 * i) * (DIM / 4) + f4];
            s.x += x.x; s.y += x.y; s.z += x.z; s.w += x.w;
        }
        smem4[t] = s;
        __syncthreads();
        if (t < 128) {
            float4 a = smem4[t], c = smem4[t + 128];
            reinterpret_cast<float4*>(partial)[(size_t)blk * (DIM / 4) + t] =
                make_float4(a.x + c.x, a.y + c.y, a.z + c.z, a.w + c.w);
        }
        __threadfence();                        // agent-scope release (wbl2)
        __syncthreads();
        if (t == 0) atomicAdd(&ctr[0], 1u);
    }

    if (blk < 32) {
        // ---- Phase B: reduce partial slice -> cs; V matvec -> vpart ----
        const int ks = blk >> 3, ec = blk & 7;
        if (t == 0) while (poll_ld(&ctr[0]) < NBLK) __builtin_amdgcn_s_sleep(2);
        __syncthreads();
        __threadfence();                        // acquire (inv) before reads
        if (t < 128) {
            const int bb = t >> 5, c4 = t & 31;
            const float4* p = reinterpret_cast<const float4*>(partial)
                            + (size_t)(bb * CPB) * (DIM / 4) + ks * 32 + c4;
            float4 s = make_float4(0.f, 0.f, 0.f, 0.f);
#pragma unroll 4
            for (int ch = 0; ch < CPB; ++ch) {
                float4 x = p[(size_t)ch * (DIM / 4)];
                s.x += x.x; s.y += x.y; s.z += x.z; s.w += x.w;
            }
            smem4[bb * 32 + c4] = s;            // cs[bb][128]
        }
        __syncthreads();
        {
            const int bb = t >> 6, el = t & 63; // bb wave-uniform -> LDS bcast
            const int e = ec * 64 + el;
            const float* w  = Wkv + (size_t)(ks * 128) * (2 * DIM) + DIM + e;
            const float* cs = smem + bb * 128;
            float s = 0.f;
#pragma unroll 8
            for (int d0 = 0; d0 < 128; ++d0) s += cs[d0] * w[(size_t)d0 * (2 * DIM)];
            vpart[(ks * BATCH + bb) * DIM + e] = s;
        }
        __threadfence();
        __syncthreads();
        if (t == 0) atomicAdd(&ctr[1], 1u);

        // ---- Phase C: vsum combine + Wout matvec -> orow ----
        const int cb = blk >> 3, fc = blk & 7;
        if (t == 0) while (poll_ld(&ctr[1]) < 32) __builtin_amdgcn_s_sleep(2);
        __syncthreads();
        __threadfence();
        for (int j = t; j < DIM; j += 256) {
            const int idx = cb * DIM + j;
            smem[j] = vpart[idx] + vpart[BATCH * DIM + idx]
                    + vpart[2 * BATCH * DIM + idx] + vpart[3 * BATCH * DIM + idx];
        }
        __syncthreads();
        {
            const int fl = t & 63, eq = t >> 6;
            const float* w2 = Wout + (size_t)(eq * 128) * DIM + fc * 64 + fl;
            float s2 = 0.f;
#pragma unroll 8
            for (int e0 = 0; e0 < 128; ++e0) s2 += smem[eq * 128 + e0] * w2[(size_t)e0 * DIM];
            smem[512 + t] = s2;
        }
        __syncthreads();
        if (t < 64) orow[cb * DIM + fc * 64 + t] =
            smem[512 + t] + smem[576 + t] + smem[640 + t] + smem[704 + t];
        __threadfence();
        __syncthreads();
        if (t == 0) atomicAdd(&ctr[2], 1u);
    }

    // ---- Phase D: broadcast orow over all q (16.8 MB write) ----
    {
        if (t == 0) while (poll_ld(&ctr[2]) < 32) __builtin_amdgcn_s_sleep(8);
        __syncthreads();
        __threadfence();                        // acquire before orow read
        const int rg = t >> 7, f4 = t & 127;
        const float4 val =
            reinterpret_cast<const float4*>(orow)[b_hi * (DIM / 4) + f4];
        float4* dst = out + (size_t)(b_hi * QLEN + sub * RPC) * (DIM / 4);
#pragma unroll
        for (int i = 0; i < 4; ++i)
            dst[(size_t)(rg + 2 * i) * (DIM / 4) + f4] = val;
    }
}

extern "C" void kernel_launch(void* const* d_in, const int* in_sizes, int n_in,
                              void* d_out, int out_size, void* d_ws, size_t ws_size,
                              hipStream_t stream) {
    // inputs: 0=query (unused), 1=context, 2=mask (unused), 3=Wq (unused), 4=Wkv, 5=Wout
    const float* ctx  = (const float*)d_in[1];
    const float* Wkv  = (const float*)d_in[4];
    const float* Wout = (const float*)d_in[5];
    unsigned* ctr  = (unsigned*)d_ws;                         // 256 B counter region
    float* partial = (float*)((char*)d_ws + 256);             // NBLK*DIM  = 2 MB
    float* vpart   = partial + (size_t)NBLK * DIM;            // 4*BATCH*DIM
    float* orow    = vpart + 4 * BATCH * DIM;                 // BATCH*DIM
    float4* out    = (float4*)d_out;

    // counters must be zeroed EVERY call (ws is not re-poisoned between replays)
    hipMemsetAsync(ctr, 0, 256, stream);
    fused_sync<<<NBLK, 256, 0, stream>>>(ctx, Wkv, Wout, partial, vpart, orow,
                                         ctr, out);
}

// Round 5
// 51.107 us; speedup vs baseline: 6.3034x; 5.0798x over previous
//
#include <hip/hip_runtime.h>

// Problem constants (match reference)
#define BATCH 4
#define QLEN 2048
#define CLEN 2048
#define DIM 512
#define NBLK1 1024          // K1 blocks: 4 per CU
#define CPB 256             // chunks per batch (NBLK1 / BATCH)
#define RPC 8               // context rows per chunk

// The reference collapses: einsum 'bqkh,bvha->bqha' has independent k and v,
// and softmax over k sums to exactly 1, so
//   out[b,q,:] = ((sum_cl context[b,cl,:]) @ Wkv[:,D:2D]) @ Wout   for every q.
// query, Wq, mask are dead inputs.
//
// 4-kernel chain; grid-wide sync via kernel boundaries (cheapest on this chip:
// both in-kernel grid-sync flavors measured 250-320us in rounds 3-4).

// ---- K1: partial column sums of context (16.8 MB HBM read, full grid) ----
__global__ __launch_bounds__(256) void k_csum_partial(const float* __restrict__ ctx,
                                                      float* __restrict__ partial) {
    __shared__ float4 red4[256];
    const int blk = blockIdx.x, t = threadIdx.x;
    const int b = blk >> 8, ch = blk & 255;
    const int rg = t >> 7, f4 = t & 127;
    const float4* src = reinterpret_cast<const float4*>(ctx)
                      + (size_t)(b * CLEN + ch * RPC) * (DIM / 4);
    float4 s = make_float4(0.f, 0.f, 0.f, 0.f);
#pragma unroll
    for (int i = 0; i < 4; ++i) {
        float4 x = src[(size_t)(rg + 2 * i) * (DIM / 4) + f4];
        s.x += x.x; s.y += x.y; s.z += x.z; s.w += x.w;
    }
    red4[t] = s;
    __syncthreads();
    if (t < 128) {
        float4 a = red4[t], c = red4[t + 128];
        reinterpret_cast<float4*>(partial)[(size_t)blk * (DIM / 4) + t] =
            make_float4(a.x + c.x, a.y + c.y, a.z + c.z, a.w + c.w);
    }
}

// ---- K2: reduce partial slice -> csum; V matvec -> vpart (32 blocks) ----
__global__ __launch_bounds__(256) void k_reduce_vsum(const float* __restrict__ partial,
                                                     const float* __restrict__ Wkv,
                                                     float* __restrict__ vpart) {
    __shared__ float4 smem4[128];              // cs[4][128] floats
    float* smem = reinterpret_cast<float*>(smem4);
    const int blk = blockIdx.x, t = threadIdx.x;
    const int ks = blk >> 3, ec = blk & 7;
    if (t < 128) {
        const int bb = t >> 5, c4 = t & 31;
        const float4* p = reinterpret_cast<const float4*>(partial)
                        + (size_t)(bb * CPB) * (DIM / 4) + ks * 32 + c4;
        float4 s = make_float4(0.f, 0.f, 0.f, 0.f);
#pragma unroll 4
        for (int ch = 0; ch < CPB; ++ch) {
            float4 x = p[(size_t)ch * (DIM / 4)];
            s.x += x.x; s.y += x.y; s.z += x.z; s.w += x.w;
        }
        smem4[bb * 32 + c4] = s;
    }
    __syncthreads();
    const int bb = t >> 6, el = t & 63;        // bb wave-uniform -> LDS broadcast
    const int e = ec * 64 + el;
    const float* w  = Wkv + (size_t)(ks * 128) * (2 * DIM) + DIM + e;
    const float* cs = smem + bb * 128;
    float s = 0.f;
#pragma unroll 8
    for (int d0 = 0; d0 < 128; ++d0) s += cs[d0] * w[(size_t)d0 * (2 * DIM)];
    vpart[(ks * BATCH + bb) * DIM + e] = s;
}

// ---- K2b: vsum combine + Wout matvec -> orow (32 blocks) ----
__global__ __launch_bounds__(256) void k_orow(const float* __restrict__ vpart,
                                              const float* __restrict__ Wout,
                                              float* __restrict__ orow) {
    __shared__ float vs[DIM];
    __shared__ float red[256];
    const int blk = blockIdx.x, t = threadIdx.x;
    const int b = blk >> 3, fc = blk & 7;
    for (int j = t; j < DIM; j += 256) {
        const int idx = b * DIM + j;
        vs[j] = vpart[idx] + vpart[BATCH * DIM + idx]
              + vpart[2 * BATCH * DIM + idx] + vpart[3 * BATCH * DIM + idx];
    }
    __syncthreads();
    const int fl = t & 63, eq = t >> 6;
    const float* w = Wout + (size_t)(eq * 128) * DIM + fc * 64 + fl;
    float s = 0.f;
#pragma unroll 8
    for (int e0 = 0; e0 < 128; ++e0) s += vs[eq * 128 + e0] * w[(size_t)e0 * DIM];
    red[t] = s;
    __syncthreads();
    if (t < 64)
        orow[b * DIM + fc * 64 + t] = red[t] + red[64 + t] + red[128 + t] + red[192 + t];
}

// ---- K3: pure stream broadcast (16.8 MB HBM write, full grid) ----
__global__ __launch_bounds__(256) void k_bcast(const float* __restrict__ orow,
                                               float4* __restrict__ out) {
    __shared__ float4 o4[BATCH * DIM / 4];     // 8 KB: full orow
    for (int j = threadIdx.x; j < BATCH * DIM / 4; j += 256)
        o4[j] = reinterpret_cast<const float4*>(orow)[j];
    __syncthreads();
    const int total4 = BATCH * QLEN * (DIM / 4);   // 2^20
    const int stride = gridDim.x * 256;
    for (int i = blockIdx.x * 256 + threadIdx.x; i < total4; i += stride)
        out[i] = o4[((i >> 18) << 7) | (i & 127)];
}

extern "C" void kernel_launch(void* const* d_in, const int* in_sizes, int n_in,
                              void* d_out, int out_size, void* d_ws, size_t ws_size,
                              hipStream_t stream) {
    // inputs: 0=query (unused), 1=context, 2=mask (unused), 3=Wq (unused), 4=Wkv, 5=Wout
    const float* ctx  = (const float*)d_in[1];
    const float* Wkv  = (const float*)d_in[4];
    const float* Wout = (const float*)d_in[5];
    float* ws = (float*)d_ws;
    float* partial = ws;                                  // NBLK1*DIM = 2 MB
    float* vpart   = partial + (size_t)NBLK1 * DIM;       // 4*BATCH*DIM
    float* orow    = vpart + 4 * BATCH * DIM;             // BATCH*DIM

    k_csum_partial<<<NBLK1, 256, 0, stream>>>(ctx, partial);
    k_reduce_vsum<<<32, 256, 0, stream>>>(partial, Wkv, vpart);
    k_orow<<<32, 256, 0, stream>>>(vpart, Wout, orow);
    k_bcast<<<2048, 256, 0, stream>>>(orow, (float4*)d_out);
}

// Round 6
// 26.698 us; speedup vs baseline: 12.0664x; 1.9143x over previous
//
#include <hip/hip_runtime.h>

// Problem constants (match reference)
#define BATCH 4
#define QLEN 2048
#define CLEN 2048
#define DIM 512
#define NBLK1 1024          // K1/K5 blocks: 4 per CU
#define CPB 256             // chunks per batch (NBLK1 / BATCH)
#define RPC 8               // rows per chunk

// The reference collapses: einsum 'bqkh,bvha->bqha' has independent k and v,
// and softmax over k sums to exactly 1, so
//   out[b,q,:] = ((sum_cl context[b,cl,:]) @ Wkv[:,D:2D]) @ Wout   for every q.
// query, Wq, mask are dead inputs.
//
// All middle phases are latency-bound, not BW-bound -> maximize loads-in-flight
// and grid width (rounds 1/2/5 showed kernel-internal serial loops dominate;
// inter-kernel gaps are cheap; in-kernel grid sync costs 100us+ on this chip).

// ---- K1: partial[blk][d] = sum of its 8 context rows (16.8 MB HBM read) ----
__global__ __launch_bounds__(256) void k1_partial(const float* __restrict__ ctx,
                                                  float4* __restrict__ partial) {
    __shared__ float4 red[256];
    const int blk = blockIdx.x, t = threadIdx.x;
    const int b = blk >> 8, ch = blk & 255;
    const int rg = t >> 7, f4 = t & 127;
    const float4* src = reinterpret_cast<const float4*>(ctx)
                      + (size_t)(b * CLEN + ch * RPC) * (DIM / 4);
    float4 s = make_float4(0.f, 0.f, 0.f, 0.f);
#pragma unroll
    for (int i = 0; i < 4; ++i) {                    // 4 independent loads
        float4 x = src[(size_t)(rg + 2 * i) * (DIM / 4) + f4];
        s.x += x.x; s.y += x.y; s.z += x.z; s.w += x.w;
    }
    red[t] = s;
    __syncthreads();
    if (t < 128) {
        float4 a = red[t], c = red[t + 128];
        partial[(size_t)blk * (DIM / 4) + t] =
            make_float4(a.x + c.x, a.y + c.y, a.z + c.z, a.w + c.w);
    }
}

// ---- K2: csum[b][col4] = sum over 256 chunk partials. 512 blocks, one
// float4 column each; every chunk load issued simultaneously (1/thread). ----
__global__ __launch_bounds__(256) void k2_reduce(const float4* __restrict__ partial,
                                                 float4* __restrict__ csum) {
    __shared__ float4 red[256];
    const int blk = blockIdx.x, t = threadIdx.x;
    const int b = blk >> 7, f4g = blk & 127;
    red[t] = partial[(size_t)(b * CPB + t) * (DIM / 4) + f4g];
    __syncthreads();
#pragma unroll
    for (int s = 128; s > 0; s >>= 1) {
        if (t < s) {
            float4 a = red[t], c = red[t + s];
            red[t] = make_float4(a.x + c.x, a.y + c.y, a.z + c.z, a.w + c.w);
        }
        __syncthreads();
    }
    if (t == 0) csum[b * (DIM / 4) + f4g] = red[0];
}

// ---- K3: vsum[b][e] = sum_d csum[b][d] * Wkv[d][DIM+e]. 128 blocks =
// (b x e-group of 16); thread = (dg 0..15, el 0..15), 32 unrolled loads. ----
__global__ __launch_bounds__(256) void k3_vsum(const float* __restrict__ csum,
                                               const float* __restrict__ Wkv,
                                               float* __restrict__ vsum) {
    __shared__ float cs[DIM];
    __shared__ float red[256];
    const int blk = blockIdx.x, t = threadIdx.x;
    const int b = blk >> 5, eg = blk & 31;
    for (int j = t; j < DIM; j += 256) cs[j] = csum[b * DIM + j];
    __syncthreads();
    const int el = t & 15, dg = t >> 4;
    const int e = eg * 16 + el;
    const float* w = Wkv + (size_t)dg * (2 * DIM) + DIM + e;   // d = i*16 + dg
    float s = 0.f;
#pragma unroll
    for (int i = 0; i < 32; ++i)
        s += cs[i * 16 + dg] * w[(size_t)i * 16 * (2 * DIM)];
    red[t] = s;
    __syncthreads();
#pragma unroll
    for (int st = 128; st >= 16; st >>= 1) {
        if (t < st) red[t] += red[t + st];
        __syncthreads();
    }
    if (t < 16) vsum[b * DIM + eg * 16 + t] = red[t];
}

// ---- K4: orow[b][f] = sum_e vsum[b][e] * Wout[e][f]. Same structure. ----
__global__ __launch_bounds__(256) void k4_orow(const float* __restrict__ vsum,
                                               const float* __restrict__ Wout,
                                               float* __restrict__ orow) {
    __shared__ float vs[DIM];
    __shared__ float red[256];
    const int blk = blockIdx.x, t = threadIdx.x;
    const int b = blk >> 5, fg = blk & 31;
    for (int j = t; j < DIM; j += 256) vs[j] = vsum[b * DIM + j];
    __syncthreads();
    const int fl = t & 15, eg2 = t >> 4;
    const int f = fg * 16 + fl;
    const float* w = Wout + (size_t)eg2 * DIM + f;             // e = i*16 + eg2
    float s = 0.f;
#pragma unroll
    for (int i = 0; i < 32; ++i)
        s += vs[i * 16 + eg2] * w[(size_t)i * 16 * DIM];
    red[t] = s;
    __syncthreads();
#pragma unroll
    for (int st = 128; st >= 16; st >>= 1) {
        if (t < st) red[t] += red[t + st];
        __syncthreads();
    }
    if (t < 16) orow[b * DIM + fg * 16 + t] = red[t];
}

// ---- K5: out[b,q,:] = orow[b,:] for all q (16.8 MB HBM write) ----
__global__ __launch_bounds__(256) void k5_bcast(const float4* __restrict__ orow4,
                                                float4* __restrict__ out) {
    const int blk = blockIdx.x, t = threadIdx.x;
    const int b = blk >> 8, qg = blk & 255;
    const int rg = t >> 7, f4 = t & 127;
    const float4 val = orow4[b * (DIM / 4) + f4];              // L2-hot
    float4* dst = out + (size_t)(b * QLEN + qg * RPC) * (DIM / 4);
#pragma unroll
    for (int i = 0; i < 4; ++i)
        dst[(size_t)(rg + 2 * i) * (DIM / 4) + f4] = val;
}

extern "C" void kernel_launch(void* const* d_in, const int* in_sizes, int n_in,
                              void* d_out, int out_size, void* d_ws, size_t ws_size,
                              hipStream_t stream) {
    // inputs: 0=query (unused), 1=context, 2=mask (unused), 3=Wq (unused), 4=Wkv, 5=Wout
    const float* ctx  = (const float*)d_in[1];
    const float* Wkv  = (const float*)d_in[4];
    const float* Wout = (const float*)d_in[5];
    float* ws = (float*)d_ws;
    float* partial = ws;                                   // NBLK1*DIM = 524288 f
    float* csum    = partial + (size_t)NBLK1 * DIM;        // BATCH*DIM = 2048 f
    float* vsum    = csum + BATCH * DIM;                   // BATCH*DIM
    float* orow    = vsum + BATCH * DIM;                   // BATCH*DIM

    k1_partial<<<NBLK1, 256, 0, stream>>>(ctx, (float4*)partial);
    k2_reduce<<<512, 256, 0, stream>>>((const float4*)partial, (float4*)csum);
    k3_vsum<<<128, 256, 0, stream>>>(csum, Wkv, vsum);
    k4_orow<<<128, 256, 0, stream>>>(vsum, Wout, orow);
    k5_bcast<<<NBLK1, 256, 0, stream>>>((const float4*)orow, (float4*)d_out);
}